// Round 4
// baseline (1043.076 us; speedup 1.0000x reference)
//
#include <hip/hip_runtime.h>
#include <math.h>

// Problem constants (fixed by setup_inputs)
#define Nn 4
#define Ll 4096
#define Ss 256
#define Cc 256
#define FC 8
#define SC 32

// ---------------------------------------------------------------------------
// Core 128x128 fp32 GEMM tile: acc[8][8] = A[row0..+128][0..256] @
// W[cb0..+128][0..256]^T + bias. 256 threads (16 tc x 16 tr), thread 8x8.
// K staged in 8 tiles of 32 with REGISTER PREFETCH of the next K-tile so the
// global-load latency hides behind the kq compute even at 1 wave/SIMD.
// LDS XOR swizzle: word (r,k) at r*32 + (k ^ 4*((r ^ (r>>3)) & 7)).
//   A-read rows 8tr+i (4 distinct/wave, swizzle-> distinct quads, bcast) OK.
//   B-read rows 8tc+c (16 distinct, quad=(c^tc)&7 -> 2-way = free) OK.
// ---------------------------------------------------------------------------
__device__ __forceinline__ void gemm_tile(
    const float* __restrict__ A, const float* __restrict__ W,
    const float* __restrict__ bias, size_t row0, int cb0,
    float* __restrict__ As, float* __restrict__ Bs, int t,
    float acc[8][8]) {
  int tc = t & 15, tr = t >> 4;

  float4 bb0 = *(const float4*)&bias[cb0 + 8 * tc];
  float4 bb1 = *(const float4*)&bias[cb0 + 8 * tc + 4];
#pragma unroll
  for (int i = 0; i < 8; i++) {
    acc[i][0] = bb0.x; acc[i][1] = bb0.y; acc[i][2] = bb0.z; acc[i][3] = bb0.w;
    acc[i][4] = bb1.x; acc[i][5] = bb1.y; acc[i][6] = bb1.z; acc[i][7] = bb1.w;
  }

  int rS = t >> 3, jS = t & 7;          // staging row (0..31 step: +32/iter), col
  float4 pa[4], pb[4];
#pragma unroll
  for (int it = 0; it < 4; it++) {
    int r = rS + 32 * it;
    pa[it] = *(const float4*)(A + (row0 + r) * Cc + 4 * jS);
    pb[it] = *(const float4*)(W + (size_t)(cb0 + r) * Cc + 4 * jS);
  }

  int sA = tr & 7, sB = tc & 7;
  for (int kt = 0; kt < 8; kt++) {
    __syncthreads();  // all reads of previous tile done before overwrite
#pragma unroll
    for (int it = 0; it < 4; it++) {
      int r = rS + 32 * it;
      int sw = (4 * jS) ^ (((r ^ (r >> 3)) & 7) << 2);
      *(float4*)&As[r * 32 + sw] = pa[it];
      *(float4*)&Bs[r * 32 + sw] = pb[it];
    }
    if (kt < 7) {
#pragma unroll
      for (int it = 0; it < 4; it++) {
        int r = rS + 32 * it;
        pa[it] = *(const float4*)(A + (row0 + r) * Cc + (kt + 1) * 32 + 4 * jS);
        pb[it] = *(const float4*)(W + (size_t)(cb0 + r) * Cc + (kt + 1) * 32 + 4 * jS);
      }
    }
    __syncthreads();

#pragma unroll
    for (int kq = 0; kq < 8; kq++) {
      float4 Bv[8];
#pragma unroll
      for (int c = 0; c < 8; c++)
        Bv[c] = *(const float4*)&Bs[(8 * tc + c) * 32 +
                                    ((4 * kq) ^ ((c ^ sB) << 2))];
#pragma unroll
      for (int i = 0; i < 8; i++) {
        float4 Av = *(const float4*)&As[(8 * tr + i) * 32 +
                                        ((4 * kq) ^ ((i ^ sA) << 2))];
#pragma unroll
        for (int c = 0; c < 8; c++) {
          acc[i][c] = fmaf(Av.x, Bv[c].x, acc[i][c]);
          acc[i][c] = fmaf(Av.y, Bv[c].y, acc[i][c]);
          acc[i][c] = fmaf(Av.z, Bv[c].z, acc[i][c]);
          acc[i][c] = fmaf(Av.w, Bv[c].w, acc[i][c]);
        }
      }
    }
  }
}

// ---------------------------------------------------------------------------
// Fused kernel 1. Blocks 0..255: x0p = x0 @ W0^T + b0 -> xn[16384][256].
// Blocks 256..287: c1 = center1 @ W1^T + b1 (M=1024, N=512), with in-block
// epilogue: per (row, fiber) l2-normalize the point half -> cpn, raw -> cval.
// ---------------------------------------------------------------------------
__global__ __launch_bounds__(256, 2) void x0p_c1_k(
    const float* __restrict__ x0, const float* __restrict__ W0,
    const float* __restrict__ b0, const float* __restrict__ center1,
    const float* __restrict__ W1, const float* __restrict__ b1,
    float* __restrict__ xn, float* __restrict__ cpn, float* __restrict__ cval) {
  __shared__ float As[128 * 32];  // 16 KB
  __shared__ float Bs[128 * 32];  // 16 KB
  int t = threadIdx.x;
  int tc = t & 15, tr = t >> 4;
  int b = blockIdx.x;
  float acc[8][8];

  if (b < 256) {
    size_t row0 = (size_t)(b >> 1) * 128;
    int cb0 = (b & 1) * 128;
    gemm_tile(x0, W0, b0, row0, cb0, As, Bs, t, acc);
#pragma unroll
    for (int i = 0; i < 8; i++) {
      float4 o0, o1;
      o0.x = acc[i][0]; o0.y = acc[i][1]; o0.z = acc[i][2]; o0.w = acc[i][3];
      o1.x = acc[i][4]; o1.y = acc[i][5]; o1.z = acc[i][6]; o1.w = acc[i][7];
      float* cr = xn + (row0 + 8 * tr + i) * Cc + cb0 + 8 * tc;
      *(float4*)cr = o0;
      *(float4*)(cr + 4) = o1;
    }
  } else {
    int b2 = b - 256;
    size_t row0 = (size_t)(b2 >> 2) * 128;   // over M=1024 (n*256+s)
    int cb0 = (b2 & 3) * 128;                // over N=512
    gemm_tile(center1, W1, b1, row0, cb0, As, Bs, t, acc);
    // epilogue: cols 8tc+c; q = col&63 (<32 -> point, else value)
    bool isPoint = (tc & 7) < 4;
#pragma unroll
    for (int i = 0; i < 8; i++) {
      float ss = 0.f;
#pragma unroll
      for (int c = 0; c < 8; c++) ss = fmaf(acc[i][c], acc[i][c], ss);
      // sum over the 4 point-threads of this 32-col group (lanes differ in
      // tc bits 0..1); value threads participate harmlessly.
      ss += __shfl_xor(ss, 1, 64);
      ss += __shfl_xor(ss, 2, 64);
      float rin = 1.f / fmaxf(sqrtf(ss), 1e-12f);
      int rowg = (int)row0 + 8 * tr + i;
      int nI = rowg >> 8, s = rowg & 255;
#pragma unroll
      for (int c = 0; c < 8; c++) {
        int col = cb0 + 8 * tc + c;
        int f = col >> 6, q = col & 63;
        size_t base = (((size_t)nI * FC + f) * Ss + s) * SC;
        if (isPoint) cpn[base + q] = acc[i][c] * rin;
        else         cval[base + (q - SC)] = acc[i][c];
      }
    }
  }
}

// ---------------------------------------------------------------------------
// sim: per block one (n,f) and 64 l-rows vs all 256 centers, K=32.
// Thread 8 rows x 8 cols; inner loop gemm-style (Bv[8] preload, Av inline)
// to keep VGPR <= 170 (launch_bounds (256,3)). Argmax of a*sim+b per row via
// 32-lane shfl_xor (min-index tie), gather c_value, scale by sigmoid(max),
// write dispatched IN PLACE over xn.
// ---------------------------------------------------------------------------
__global__ __launch_bounds__(256, 3) void sim_k(
    float* __restrict__ xn, const float* __restrict__ cpn,
    const float* __restrict__ cval, const float* __restrict__ alphap,
    const float* __restrict__ betap) {
  __shared__ float Xs[64 * 32];    //  8 KB
  __shared__ float Csh[256 * 32];  // 32 KB
  int t = threadIdx.x;
  int tc = t & 31, tr = t >> 5;  // 32 thread-cols x 8 thread-rows
  int lt = blockIdx.x & 63;      // l-tile of 64
  int nf = blockIdx.x >> 6;      // 0..31
  int f = nf & 7, nI = nf >> 3;
  int l0 = lt * 64;

  const float* cp = cpn + (size_t)nf * Ss * SC;
#pragma unroll
  for (int it = 0; it < 8; it++) {
    int i2 = t + 256 * it;
    int c = i2 >> 3, j = i2 & 7;
    float4 v = *(const float4*)(cp + c * SC + 4 * j);
    *(float4*)&Csh[c * 32 + ((4 * j) ^ (((c ^ (c >> 3)) & 7) << 2))] = v;
  }
#pragma unroll
  for (int it = 0; it < 2; it++) {
    int i2 = t + 256 * it;
    int r = i2 >> 3, j = i2 & 7;
    float4 v = *(const float4*)(xn + ((size_t)nI * Ll + l0 + r) * Cc + f * SC + 4 * j);
    float ss = v.x * v.x + v.y * v.y + v.z * v.z + v.w * v.w;
    ss += __shfl_xor(ss, 1, 64);
    ss += __shfl_xor(ss, 2, 64);
    ss += __shfl_xor(ss, 4, 64);
    float rin = 1.f / fmaxf(sqrtf(ss), 1e-12f);
    v.x *= rin; v.y *= rin; v.z *= rin; v.w *= rin;
    *(float4*)&Xs[r * 32 + ((4 * j) ^ (((r ^ (r >> 3)) & 7) << 2))] = v;
  }
  __syncthreads();

  float acc[8][8];
#pragma unroll
  for (int i = 0; i < 8; i++)
#pragma unroll
    for (int c = 0; c < 8; c++) acc[i][c] = 0.f;

  int sB = tc & 7, sA = tr & 7;
#pragma unroll
  for (int kq = 0; kq < 8; kq++) {
    float4 Bv[8];
#pragma unroll
    for (int c = 0; c < 8; c++)
      Bv[c] = *(const float4*)&Csh[(8 * tc + c) * 32 +
                                   ((4 * kq) ^ ((c ^ sB) << 2))];
#pragma unroll
    for (int i = 0; i < 8; i++) {
      float4 Av = *(const float4*)&Xs[(8 * tr + i) * 32 +
                                      ((4 * kq) ^ ((i ^ sA) << 2))];
#pragma unroll
      for (int c = 0; c < 8; c++) {
        acc[i][c] = fmaf(Av.x, Bv[c].x, acc[i][c]);
        acc[i][c] = fmaf(Av.y, Bv[c].y, acc[i][c]);
        acc[i][c] = fmaf(Av.z, Bv[c].z, acc[i][c]);
        acc[i][c] = fmaf(Av.w, Bv[c].w, acc[i][c]);
      }
    }
  }

  float a = alphap[0], bt = betap[0];
#pragma unroll
  for (int i = 0; i < 8; i++) {
    float best = -3.0e38f;
    int bi = 0;
#pragma unroll
    for (int c = 0; c < 8; c++) {
      float tv = fmaf(a, acc[i][c], bt);
      if (tv > best) { best = tv; bi = 8 * tc + c; }
    }
#pragma unroll
    for (int m = 1; m <= 16; m <<= 1) {
      float ov = __shfl_xor(best, m, 64);
      int oi = __shfl_xor(bi, m, 64);
      if (ov > best || (ov == best && oi < bi)) { best = ov; bi = oi; }
    }
    float mv = 1.f / (1.f + expf(-best));
    float val = cval[((size_t)nf * Ss + bi) * SC + tc] * mv;
    xn[((size_t)nI * Ll + l0 + 8 * tr + i) * Cc + f * SC + tc] = val;
  }
}

// ---------------------------------------------------------------------------
// out = dispatched @ Wm^T + bm
// ---------------------------------------------------------------------------
__global__ __launch_bounds__(256, 2) void out_k(
    const float* __restrict__ xn, const float* __restrict__ Wm,
    const float* __restrict__ bm, float* __restrict__ out) {
  __shared__ float As[128 * 32];
  __shared__ float Bs[128 * 32];
  int t = threadIdx.x;
  int tc = t & 15, tr = t >> 4;
  size_t row0 = (size_t)(blockIdx.x >> 1) * 128;
  int cb0 = (blockIdx.x & 1) * 128;
  float acc[8][8];
  gemm_tile(xn, Wm, bm, row0, cb0, As, Bs, t, acc);
#pragma unroll
  for (int i = 0; i < 8; i++) {
    float4 o0, o1;
    o0.x = acc[i][0]; o0.y = acc[i][1]; o0.z = acc[i][2]; o0.w = acc[i][3];
    o1.x = acc[i][4]; o1.y = acc[i][5]; o1.z = acc[i][6]; o1.w = acc[i][7];
    float* cr = out + (row0 + 8 * tr + i) * Cc + cb0 + 8 * tc;
    *(float4*)cr = o0;
    *(float4*)(cr + 4) = o1;
  }
}

// ---------------------------------------------------------------------------
extern "C" void kernel_launch(void* const* d_in, const int* in_sizes, int n_in,
                              void* d_out, int out_size, void* d_ws, size_t ws_size,
                              hipStream_t stream) {
  const float* x0      = (const float*)d_in[0];
  const float* center1 = (const float*)d_in[1];
  const float* W0      = (const float*)d_in[2];
  const float* b0      = (const float*)d_in[3];
  const float* W1      = (const float*)d_in[4];
  const float* b1      = (const float*)d_in[5];
  const float* Wm      = (const float*)d_in[6];
  const float* bm      = (const float*)d_in[7];
  const float* alpha   = (const float*)d_in[8];
  const float* beta    = (const float*)d_in[9];
  float* out = (float*)d_out;
  float* ws  = (float*)d_ws;

  float* xn   = ws;                              // 16 MB: x0p, then dispatched in-place
  float* cpn  = xn + (size_t)Nn * Ll * Cc;       // 1 MB
  float* cval = cpn + (size_t)Nn * FC * Ss * SC; // 1 MB  (total 18 MB)

  // x0p GEMM (256 blocks) + c1 GEMM/normalize/split (32 blocks), fused
  x0p_c1_k<<<dim3(288), dim3(256), 0, stream>>>(
      x0, W0, b0, center1, W1, b1, xn, cpn, cval);
  // sim + argmax + gather + scale, in place over xn
  sim_k<<<dim3(32 * 64), dim3(256), 0, stream>>>(xn, cpn, cval, alpha, beta);
  // out = dispatched @ Wm^T + bm
  out_k<<<dim3(256), dim3(256), 0, stream>>>(xn, Wm, bm, out);
}

// Round 5
// 203.515 us; speedup vs baseline: 5.1253x; 5.1253x over previous
//
#include <hip/hip_runtime.h>
#include <math.h>

// Problem constants (fixed by setup_inputs)
#define Nn 4
#define Ll 4096
#define Ss 256
#define Cc 256
#define FC 8
#define SC 32

#define LSTR 132                      // k-major LDS stride (words), mult of 4
#define PHI(k) ((((k) >> 3) & 3) << 2)  // row-XOR: spreads staging banks

// ---------------------------------------------------------------------------
// k-major fp32 GEMM tile: acc[8][8] = A[row0..+128][:] @ W[cb0..+128][:]^T + b.
// 256 threads; thread rows {4tr+i, 64+4tr+i}, cols {4tc+c, 64+4tc+c}.
// LDS word (r,k) at k*132 + (r ^ PHI(k)). Inner loop per k: 4 ds_read_b128
// (immediate offsets, <=2-way banks) + 64 fmaf. Register prefetch across kt.
// ---------------------------------------------------------------------------
__device__ __forceinline__ void gemm_tile(
    const float* __restrict__ A, const float* __restrict__ W,
    const float* __restrict__ bias, size_t row0, int cb0,
    float* __restrict__ As, float* __restrict__ Bs, int t, float acc[8][8]) {
  int tc = t & 15, tr = (t >> 4) & 15;
  int rS = t >> 3, jS = t & 7;  // staging: row rS+32it, k-chunk 4jS..4jS+3

  float4 bb0 = *(const float4*)&bias[cb0 + 4 * tc];
  float4 bb1 = *(const float4*)&bias[cb0 + 64 + 4 * tc];
#pragma unroll
  for (int i = 0; i < 8; i++) {
    acc[i][0] = bb0.x; acc[i][1] = bb0.y; acc[i][2] = bb0.z; acc[i][3] = bb0.w;
    acc[i][4] = bb1.x; acc[i][5] = bb1.y; acc[i][6] = bb1.z; acc[i][7] = bb1.w;
  }

  float4 pa[4], pb[4];
#pragma unroll
  for (int it = 0; it < 4; it++) {
    pa[it] = *(const float4*)(A + (row0 + rS + 32 * it) * Cc + 4 * jS);
    pb[it] = *(const float4*)(W + (size_t)(cb0 + rS + 32 * it) * Cc + 4 * jS);
  }

  int xsw = 4 * (jS >> 1);  // PHI(4jS+q) = 4*(jS>>1), q<4
  for (int kt = 0; kt < 8; kt++) {
    __syncthreads();
#pragma unroll
    for (int it = 0; it < 4; it++) {
      int r = rS + 32 * it;
      int rw = r ^ xsw;
      const float* paf = (const float*)&pa[it];
      const float* pbf = (const float*)&pb[it];
#pragma unroll
      for (int q = 0; q < 4; q++) {
        As[(4 * jS + q) * LSTR + rw] = paf[q];
        Bs[(4 * jS + q) * LSTR + rw] = pbf[q];
      }
    }
    if (kt < 7) {
#pragma unroll
      for (int it = 0; it < 4; it++) {
        pa[it] = *(const float4*)(A + (row0 + rS + 32 * it) * Cc + (kt + 1) * 32 + 4 * jS);
        pb[it] = *(const float4*)(W + (size_t)(cb0 + rS + 32 * it) * Cc + (kt + 1) * 32 + 4 * jS);
      }
    }
    __syncthreads();

#pragma unroll 8
    for (int k = 0; k < 32; k++) {
      int ph = PHI(k);
      int ra = (4 * tr) ^ ph, rb = (4 * tc) ^ ph;
      float4 a0 = *(const float4*)&As[k * LSTR + ra];
      float4 a1 = *(const float4*)&As[k * LSTR + 64 + ra];
      float4 b0 = *(const float4*)&Bs[k * LSTR + rb];
      float4 b1 = *(const float4*)&Bs[k * LSTR + 64 + rb];
      const float* af0 = (const float*)&a0;
      const float* af1 = (const float*)&a1;
      const float* bf0 = (const float*)&b0;
      const float* bf1 = (const float*)&b1;
#pragma unroll
      for (int i = 0; i < 4; i++) {
#pragma unroll
        for (int c = 0; c < 4; c++) {
          acc[i][c]         = fmaf(af0[i], bf0[c], acc[i][c]);
          acc[i][c + 4]     = fmaf(af0[i], bf1[c], acc[i][c + 4]);
          acc[i + 4][c]     = fmaf(af1[i], bf0[c], acc[i + 4][c]);
          acc[i + 4][c + 4] = fmaf(af1[i], bf1[c], acc[i + 4][c + 4]);
        }
      }
    }
  }
}

__device__ __forceinline__ void store_tile(
    float* __restrict__ C, size_t row0, int cb0, int ldc, int t,
    const float acc[8][8]) {
  int tc = t & 15, tr = (t >> 4) & 15;
#pragma unroll
  for (int i = 0; i < 8; i++) {
    int r = (i < 4) ? (4 * tr + i) : (64 + 4 * tr + (i - 4));
    float4 o0, o1;
    o0.x = acc[i][0]; o0.y = acc[i][1]; o0.z = acc[i][2]; o0.w = acc[i][3];
    o1.x = acc[i][4]; o1.y = acc[i][5]; o1.z = acc[i][6]; o1.w = acc[i][7];
    float* cr = C + (row0 + r) * (size_t)ldc + cb0;
    *(float4*)(cr + 4 * tc) = o0;
    *(float4*)(cr + 64 + 4 * tc) = o1;
  }
}

// ---------------------------------------------------------------------------
// Fused kernel 1. Blocks 0..255: x0p = x0 @ W0^T + b0 -> xn[16384][256].
// Blocks 256..287: c1 = center1 @ W1^T + b1 (M=1024,N=512) with split/norm
// epilogue -> cpn (l2-normalized point half), cval (raw value half).
// ---------------------------------------------------------------------------
__global__ __launch_bounds__(256) void x0p_c1_k(
    const float* __restrict__ x0, const float* __restrict__ W0,
    const float* __restrict__ b0, const float* __restrict__ center1,
    const float* __restrict__ W1, const float* __restrict__ b1,
    float* __restrict__ xn, float* __restrict__ cpn, float* __restrict__ cval) {
  __shared__ float As[32 * LSTR];  // 16.5 KB
  __shared__ float Bs[32 * LSTR];  // 16.5 KB
  int t = threadIdx.x;
  int tc = t & 15, tr = (t >> 4) & 15;
  int b = blockIdx.x;
  float acc[8][8];

  if (b < 256) {
    size_t row0 = (size_t)(b >> 1) * 128;
    int cb0 = (b & 1) * 128;
    gemm_tile(x0, W0, b0, row0, cb0, As, Bs, t, acc);
    store_tile(xn, row0, cb0, Cc, t, acc);
  } else {
    int b2 = b - 256;
    size_t row0 = (size_t)(b2 >> 2) * 128;  // M=1024 (n*256+s)
    int cb0 = (b2 & 3) * 128;               // N=512
    gemm_tile(center1, W1, b1, row0, cb0, As, Bs, t, acc);
    // epilogue: thread cols = {cb0+4tc+c} (fiber fb+0) and {cb0+64+4tc+c}
    // (fiber fb+1); q = 4tc+c in 0..63; point iff q<32 <=> tc<8.
    int fb = cb0 >> 6;
#pragma unroll
    for (int i = 0; i < 8; i++) {
      int r = (i < 4) ? (4 * tr + i) : (64 + 4 * tr + (i - 4));
      int crow = (int)row0 + r;
      int nI = crow >> 8, s = crow & 255;
#pragma unroll
      for (int h = 0; h < 2; h++) {
        float s0 = acc[i][4 * h + 0], s1 = acc[i][4 * h + 1];
        float s2 = acc[i][4 * h + 2], s3 = acc[i][4 * h + 3];
        float ss = s0 * s0 + s1 * s1 + s2 * s2 + s3 * s3;
        ss += __shfl_xor(ss, 1, 64);
        ss += __shfl_xor(ss, 2, 64);
        ss += __shfl_xor(ss, 4, 64);  // sums tc-octet (point lanes tc<8)
        float rin = 1.f / fmaxf(sqrtf(ss), 1e-12f);
        int f = fb + h;
        size_t base = (((size_t)nI * FC + f) * Ss + s) * SC;
        if (tc < 8) {
          float4 o; o.x = s0 * rin; o.y = s1 * rin; o.z = s2 * rin; o.w = s3 * rin;
          *(float4*)&cpn[base + 4 * tc] = o;
        } else {
          float4 o; o.x = s0; o.y = s1; o.z = s2; o.w = s3;
          *(float4*)&cval[base + 4 * (tc - 8)] = o;
        }
      }
    }
  }
}

// ---------------------------------------------------------------------------
// sim: per block one (n,f), 64 l-rows vs all 256 centers, K=32 (k-major LDS).
// Thread: 4 rows (4tr+i) x 16 cols (64g+4tc+c). Per k: 5 ds_read_b128 + 64
// fmaf. X rows l2-normalized during staging. Argmax of a*sim+b per row via
// 16-lane shfl_xor (min-index tie); gather c_value, scale by sigmoid(max),
// write dispatched IN PLACE over xn (block owns its region exclusively).
// ---------------------------------------------------------------------------
__global__ __launch_bounds__(256) void sim_k(
    float* __restrict__ xn, const float* __restrict__ cpn,
    const float* __restrict__ cval, const float* __restrict__ alphap,
    const float* __restrict__ betap) {
  __shared__ float Xs[32 * 68];    //  8.5 KB (stride 68)
  __shared__ float Cs[32 * 260];   // 32.5 KB (stride 260)
  int t = threadIdx.x;
  int tc = t & 15, tr = t >> 4;    // tr 0..15 -> rows 4tr..4tr+3
  int lt = blockIdx.x & 63;
  int nf = blockIdx.x >> 6;        // 0..31
  int f = nf & 7, nI = nf >> 3;
  int l0 = lt * 64;
  int jS = t & 7;
  int xsw = 4 * (jS >> 1);         // PHI(4jS+q)

  const float* cp = cpn + (size_t)nf * Ss * SC;
#pragma unroll
  for (int it = 0; it < 8; it++) {
    int i2 = t + 256 * it;
    int c = i2 >> 3, j = i2 & 7;
    float4 v = *(const float4*)(cp + c * SC + 4 * j);
    const float* vf = (const float*)&v;
    int cw = c ^ xsw;
#pragma unroll
    for (int q = 0; q < 4; q++) Cs[(4 * j + q) * 260 + cw] = vf[q];
  }
#pragma unroll
  for (int it = 0; it < 2; it++) {
    int i2 = t + 256 * it;
    int r = i2 >> 3, j = i2 & 7;
    float4 v = *(const float4*)(xn + ((size_t)nI * Ll + l0 + r) * Cc + f * SC + 4 * j);
    float ss = v.x * v.x + v.y * v.y + v.z * v.z + v.w * v.w;
    ss += __shfl_xor(ss, 1, 64);
    ss += __shfl_xor(ss, 2, 64);
    ss += __shfl_xor(ss, 4, 64);  // sums the 8 j-lanes of this row
    float rin = 1.f / fmaxf(sqrtf(ss), 1e-12f);
    v.x *= rin; v.y *= rin; v.z *= rin; v.w *= rin;
    const float* vf = (const float*)&v;
    int rw = r ^ xsw;
#pragma unroll
    for (int q = 0; q < 4; q++) Xs[(4 * j + q) * 68 + rw] = vf[q];
  }
  __syncthreads();

  float acc[4][16];
#pragma unroll
  for (int i = 0; i < 4; i++)
#pragma unroll
    for (int c = 0; c < 16; c++) acc[i][c] = 0.f;

#pragma unroll 8
  for (int k = 0; k < 32; k++) {
    int ph = PHI(k);
    float4 xa = *(const float4*)&Xs[k * 68 + ((4 * tr) ^ ph)];
    const float* xf = (const float*)&xa;
    int rb = (4 * tc) ^ ph;
#pragma unroll
    for (int g = 0; g < 4; g++) {
      float4 cv = *(const float4*)&Cs[k * 260 + 64 * g + rb];
      const float* cf = (const float*)&cv;
#pragma unroll
      for (int i = 0; i < 4; i++) {
#pragma unroll
        for (int c = 0; c < 4; c++)
          acc[i][4 * g + c] = fmaf(xf[i], cf[c], acc[i][4 * g + c]);
      }
    }
  }

  float a = alphap[0], bt = betap[0];
#pragma unroll
  for (int i = 0; i < 4; i++) {
    float best = -3.0e38f;
    int bi = 0;
#pragma unroll
    for (int g = 0; g < 4; g++) {
#pragma unroll
      for (int c = 0; c < 4; c++) {
        float tv = fmaf(a, acc[i][4 * g + c], bt);
        int s = 64 * g + 4 * tc + c;  // increasing within thread
        if (tv > best) { best = tv; bi = s; }
      }
    }
#pragma unroll
    for (int m = 1; m <= 8; m <<= 1) {  // reduce across the 16 tc-lanes
      float ov = __shfl_xor(best, m, 64);
      int oi = __shfl_xor(bi, m, 64);
      if (ov > best || (ov == best && oi < bi)) { best = ov; bi = oi; }
    }
    float mv = 1.f / (1.f + expf(-best));
    const float* cvp = cval + ((size_t)nf * Ss + bi) * SC;
    float* orow = xn + ((size_t)nI * Ll + l0 + 4 * tr + i) * Cc + f * SC;
    orow[tc] = cvp[tc] * mv;
    orow[tc + 16] = cvp[tc + 16] * mv;
  }
}

// ---------------------------------------------------------------------------
// out = dispatched @ Wm^T + bm
// ---------------------------------------------------------------------------
__global__ __launch_bounds__(256) void out_k(
    const float* __restrict__ xn, const float* __restrict__ Wm,
    const float* __restrict__ bm, float* __restrict__ out) {
  __shared__ float As[32 * LSTR];
  __shared__ float Bs[32 * LSTR];
  int t = threadIdx.x;
  size_t row0 = (size_t)(blockIdx.x >> 1) * 128;
  int cb0 = (blockIdx.x & 1) * 128;
  float acc[8][8];
  gemm_tile(xn, Wm, bm, row0, cb0, As, Bs, t, acc);
  store_tile(out, row0, cb0, Cc, t, acc);
}

// ---------------------------------------------------------------------------
extern "C" void kernel_launch(void* const* d_in, const int* in_sizes, int n_in,
                              void* d_out, int out_size, void* d_ws, size_t ws_size,
                              hipStream_t stream) {
  const float* x0      = (const float*)d_in[0];
  const float* center1 = (const float*)d_in[1];
  const float* W0      = (const float*)d_in[2];
  const float* b0      = (const float*)d_in[3];
  const float* W1      = (const float*)d_in[4];
  const float* b1      = (const float*)d_in[5];
  const float* Wm      = (const float*)d_in[6];
  const float* bm      = (const float*)d_in[7];
  const float* alpha   = (const float*)d_in[8];
  const float* beta    = (const float*)d_in[9];
  float* out = (float*)d_out;
  float* ws  = (float*)d_ws;

  float* xn   = ws;                              // 16 MB: x0p, then dispatched in-place
  float* cpn  = xn + (size_t)Nn * Ll * Cc;       // 1 MB
  float* cval = cpn + (size_t)Nn * FC * Ss * SC; // 1 MB  (total 18 MB)

  x0p_c1_k<<<dim3(288), dim3(256), 0, stream>>>(
      x0, W0, b0, center1, W1, b1, xn, cpn, cval);
  sim_k<<<dim3(32 * 64), dim3(256), 0, stream>>>(xn, cpn, cval, alpha, beta);
  out_k<<<dim3(256), dim3(256), 0, stream>>>(xn, Wm, bm, out);
}